// Round 3
// baseline (369.896 us; speedup 1.0000x reference)
//
#include <hip/hip_runtime.h>

// out = x + 0.002 * einsum('bci,bij->bcj', f, softmax_i(einsum('bci,bcj->bij', f, f)))
// x: [8, 128, 64, 64] fp32.  b=8, c=d=128, n=wh=4096.
// Flash attention, Q=K=V=Ft (n x d), softmax over keys.
// Swapped-QK^T layout: S^T[key][q] per lane -> softmax mostly in-register.
// ws: Ft bf16 [b][n][c] = 8 MB.

typedef __bf16 bf16;
typedef bf16 bf16x4 __attribute__((ext_vector_type(4)));
typedef bf16 bf16x8 __attribute__((ext_vector_type(8)));
typedef float f32x4 __attribute__((ext_vector_type(4)));

#define BATCH 8
#define CD 128
#define NN 4096
#define QBLK 64
#define KVB 64
#define NT (NN / KVB)
// All strides: rows 16B-aligned, uniform bank-slot spread ((row + l4) mod 8).
#define KTS 136   // kt row stride: 272 B = 17*16
#define VTS 72    // vt row stride: 144 B =  9*16
#define PTS 72    // p  row stride: 144 B =  9*16

// ---------------- kernel 1: x [b][c][n] f32 -> Ft [b][n][c] bf16 ----------------
__global__ __launch_bounds__(256) void transpose_to_bf16(const float* __restrict__ x,
                                                         bf16* __restrict__ ft) {
    __shared__ float tile[32][33];
    const int n0 = blockIdx.x * 32;
    const int c0 = blockIdx.y * 32;
    const int b  = blockIdx.z;
    const int tx = threadIdx.x & 7;    // quad index
    const int ty = threadIdx.x >> 3;   // row 0..31

    // load: 32 c-rows x 32 n, f32x4 per lane (coalesced 128B/row)
    f32x4 v = *reinterpret_cast<const f32x4*>(
        x + ((size_t)b * CD + c0 + ty) * NN + n0 + tx * 4);
#pragma unroll
    for (int e = 0; e < 4; e++) tile[ty][tx * 4 + e] = v[e];
    __syncthreads();

    // store: n-row = ty, c-quad = tx, bf16x4 per lane
    bf16x4 o;
#pragma unroll
    for (int e = 0; e < 4; e++) o[e] = (bf16)tile[tx * 4 + e][ty];
    *reinterpret_cast<bf16x4*>(
        ft + ((size_t)b * NN + n0 + ty) * CD + c0 + tx * 4) = o;
}

// ---------------- kernel 2: flash attention + fused residual ----------------
// 512 blocks (8 batch x 64 q-tiles), 256 threads (4 waves, 16 q-rows each).
// KV loop: 64 keys/iter, double-buffered LDS, 1 barrier/iter.
__global__ __launch_bounds__(256, 2) void attn_kernel(const float* __restrict__ x,
                                                      const bf16* __restrict__ ft,
                                                      float* __restrict__ out) {
    const int tid = threadIdx.x;
    const int w   = tid >> 6;
    const int l   = tid & 63;
    const int l15 = l & 15;
    const int l4  = l >> 4;

    const int batch = blockIdx.x >> 6;
    const int q0    = (blockIdx.x & 63) * QBLK;

    const bf16*  ftb = ft + (size_t)batch * NN * CD;
    const float* xb  = x  + (size_t)batch * CD * NN;

    __shared__ union {
        struct {
            bf16 kt[2][KVB][KTS];   // [key][c]   34816 B
            bf16 vt[2][CD][VTS];    // [c][key]   36864 B (== x layout, no transpose)
            bf16 p[4][16][PTS];     // per-wave P  9216 B
        } s;
        float o[QBLK][CD + 4];      // epilogue   33792 B
    } sm;

    // Q fragments (B-frag of swapped QK^T, A-frag of PV): lane holds
    // Q[q = q0+w*16+l15][c = ct*32 + l4*8 + e]
    bf16x8 qf[4];
    {
        const bf16* qrow = ftb + (size_t)(q0 + w * 16 + l15) * CD + l4 * 8;
#pragma unroll
        for (int ct = 0; ct < 4; ct++)
            qf[ct] = *reinterpret_cast<const bf16x8*>(qrow + ct * 32);
    }

    // staging geometry: 16 lanes per row-chunk
    const int srow = tid >> 4;   // 0..15
    const int sch  = tid & 15;   // 0..15

    bf16x8 kreg[4];
    f32x4  vreg[8];

    auto stage_load = [&](int i0) {
#pragma unroll
        for (int j = 0; j < 4; j++)   // kt: 64 rows x 256B, bf16x8/lane
            kreg[j] = *reinterpret_cast<const bf16x8*>(
                ftb + (size_t)(i0 + j * 16 + srow) * CD + sch * 8);
#pragma unroll
        for (int j = 0; j < 8; j++)   // vt: 128 rows x 256B of x, f32x4/lane
            vreg[j] = *reinterpret_cast<const f32x4*>(
                xb + (size_t)(j * 16 + srow) * NN + i0 + sch * 4);
    };
    auto stage_write = [&](int buf) {
#pragma unroll
        for (int j = 0; j < 4; j++)
            *reinterpret_cast<bf16x8*>(&sm.s.kt[buf][j * 16 + srow][sch * 8]) = kreg[j];
#pragma unroll
        for (int j = 0; j < 8; j++) {
            bf16x4 t;
#pragma unroll
            for (int e = 0; e < 4; e++) t[e] = (bf16)vreg[j][e];
            *reinterpret_cast<bf16x4*>(&sm.s.vt[buf][j * 16 + srow][sch * 4]) = t;
        }
    };

    const f32x4 zero = {0.0f, 0.0f, 0.0f, 0.0f};
    f32x4 oacc[8];
#pragma unroll
    for (int i = 0; i < 8; i++) oacc[i] = zero;
    float m_run = -1e30f;   // running max for q = l15 (this lane's q-column)
    float l_par = 0.0f;     // PARTIAL sum over this lane's key share (l4 group)

    stage_load(0);
    stage_write(0);
    __syncthreads();

    for (int it = 0; it < NT; ++it) {
        const int cur = it & 1;
        if (it + 1 < NT) stage_load((it + 1) * KVB);   // in flight during compute

        // ---- swapped QK^T: S^T[key][q], 16 MFMA ----
        // lane holds s[g][r] = S[key = g*16 + l4*4 + r][q = l15]
        f32x4 s[4];
        __builtin_amdgcn_s_setprio(1);
#pragma unroll
        for (int g = 0; g < 4; g++) {
            s[g] = zero;
#pragma unroll
            for (int ct = 0; ct < 4; ct++) {
                bf16x8 kf = *reinterpret_cast<const bf16x8*>(
                    &sm.s.kt[cur][g * 16 + l15][ct * 32 + l4 * 8]);
                s[g] = __builtin_amdgcn_mfma_f32_16x16x32_bf16(kf, qf[ct], s[g], 0, 0, 0);
            }
        }
        __builtin_amdgcn_s_setprio(0);

        // ---- softmax over keys, mostly in-register ----
        // in-lane max over 16 values, then reduce over the 4 l4-lanes
        float mp;
        {
            float m0 = fmaxf(fmaxf(s[0][0], s[0][1]), fmaxf(s[0][2], s[0][3]));
            float m1 = fmaxf(fmaxf(s[1][0], s[1][1]), fmaxf(s[1][2], s[1][3]));
            float m2 = fmaxf(fmaxf(s[2][0], s[2][1]), fmaxf(s[2][2], s[2][3]));
            float m3 = fmaxf(fmaxf(s[3][0], s[3][1]), fmaxf(s[3][2], s[3][3]));
            mp = fmaxf(fmaxf(m0, m1), fmaxf(m2, m3));
        }
        mp = fmaxf(mp, __shfl_xor(mp, 16));
        mp = fmaxf(mp, __shfl_xor(mp, 32));

        if (__any(mp > m_run + 8.0f)) {   // defer-max rescale (rare)
            const float mn    = fmaxf(m_run, mp);
            const float alpha = __expf(m_run - mn);
            m_run = mn;
            l_par *= alpha;
            float a[4];
#pragma unroll
            for (int r = 0; r < 4; r++) a[r] = __shfl(alpha, l4 * 4 + r);
#pragma unroll
            for (int ct = 0; ct < 8; ct++)
#pragma unroll
                for (int r = 0; r < 4; r++) oacc[ct][r] *= a[r];
        }

        // exp + per-lane partial sum (no cross-lane reduce here)
        float pe[4][4];
        float ps = 0.0f;
#pragma unroll
        for (int g = 0; g < 4; g++)
#pragma unroll
            for (int r = 0; r < 4; r++) {
                pe[g][r] = __expf(s[g][r] - m_run);
                ps += pe[g][r];
            }
        l_par += ps;

        // ---- P -> LDS (vectorized b64 writes), read back as A-frags ----
#pragma unroll
        for (int g = 0; g < 4; g++) {
            bf16x4 t;
#pragma unroll
            for (int r = 0; r < 4; r++) t[r] = (bf16)pe[g][r];
            *reinterpret_cast<bf16x4*>(&sm.s.p[w][l15][g * 16 + l4 * 4]) = t;
        }
        bf16x8 pf0 = *reinterpret_cast<const bf16x8*>(&sm.s.p[w][l15][l4 * 8]);
        bf16x8 pf1 = *reinterpret_cast<const bf16x8*>(&sm.s.p[w][l15][32 + l4 * 8]);

        // ---- PV: O[q][c], 16 MFMA ----
        __builtin_amdgcn_s_setprio(1);
#pragma unroll
        for (int ct = 0; ct < 8; ct++) {
            bf16x8 vf0 = *reinterpret_cast<const bf16x8*>(
                &sm.s.vt[cur][ct * 16 + l15][l4 * 8]);
            bf16x8 vf1 = *reinterpret_cast<const bf16x8*>(
                &sm.s.vt[cur][ct * 16 + l15][32 + l4 * 8]);
            oacc[ct] = __builtin_amdgcn_mfma_f32_16x16x32_bf16(pf0, vf0, oacc[ct], 0, 0, 0);
            oacc[ct] = __builtin_amdgcn_mfma_f32_16x16x32_bf16(pf1, vf1, oacc[ct], 0, 0, 0);
        }
        __builtin_amdgcn_s_setprio(0);

        if (it + 1 < NT) stage_write(cur ^ 1);   // vmcnt wait lands here
        __syncthreads();
    }

    // ---- epilogue: finish deferred sum, normalize, fused residual ----
    float L = l_par;
    L += __shfl_xor(L, 16);
    L += __shfl_xor(L, 32);          // full denominator for q = l15
    float rl[4];
#pragma unroll
    for (int r = 0; r < 4; r++) rl[r] = 1.0f / __shfl(L, l4 * 4 + r);

#pragma unroll
    for (int r = 0; r < 4; r++)
#pragma unroll
        for (int ct = 0; ct < 8; ct++)
            sm.o[w * 16 + l4 * 4 + r][ct * 16 + l15] = oacc[ct][r] * rl[r];
    __syncthreads();

    const size_t xbase = (size_t)batch * CD * NN;
    for (int idx = tid; idx < QBLK * CD; idx += 256) {
        const int c = idx >> 6;
        const int q = idx & 63;
        const size_t g = xbase + (size_t)c * NN + q0 + q;
        out[g] = x[g] + 0.002f * sm.o[q][c];
    }
}

extern "C" void kernel_launch(void* const* d_in, const int* in_sizes, int n_in,
                              void* d_out, int out_size, void* d_ws, size_t ws_size,
                              hipStream_t stream) {
    const float* x = (const float*)d_in[0];
    float* out = (float*)d_out;
    bf16* ft = (bf16*)d_ws;   // 8 MB

    dim3 tb1(256);
    dim3 tg1(NN / 32, CD / 32, BATCH);
    transpose_to_bf16<<<tg1, tb1, 0, stream>>>(x, ft);

    attn_kernel<<<512, 256, 0, stream>>>(x, ft, out);
}

// Round 4
// 185.901 us; speedup vs baseline: 1.9897x; 1.9897x over previous
//
#include <hip/hip_runtime.h>

// out = x + 0.002 * einsum('bci,bij->bcj', f, softmax_i(einsum('bci,bcj->bij', f, f)))
// x: [8, 128, 64, 64] fp32.  b=8, c=d=128, n=wh=4096.
// Flash attention, Q=K=V=Ft (n x d), softmax over keys.
// Swapped-QK^T (S^T per lane) + T2 XOR-swizzled LDS (byte ^= (row&7)<<4).
// ws: Ft bf16 [b][n][c] = 8 MB.

typedef __bf16 bf16;
typedef bf16 bf16x4 __attribute__((ext_vector_type(4)));
typedef bf16 bf16x8 __attribute__((ext_vector_type(8)));
typedef float f32x4 __attribute__((ext_vector_type(4)));

#define BATCH 8
#define CD 128
#define NN 4096
#define QBLK 64
#define KVB 64
#define NT (NN / KVB)

// XOR swizzle: linear power-of-2 rows, byte column ^ ((row&7)<<4).
#define KT_BY(row, colb) (((row) << 8) + ((colb) ^ (((row) & 7) << 4)))   // 256 B rows
#define VT_BY(row, colb) (((row) << 7) + ((colb) ^ (((row) & 7) << 4)))   // 128 B rows
#define PT_BY(row, colb) (((row) << 7) + ((colb) ^ (((row) & 7) << 4)))   // 128 B rows

// ---------------- kernel 1: x [b][c][n] f32 -> Ft [b][n][c] bf16 ----------------
__global__ __launch_bounds__(256) void transpose_to_bf16(const float* __restrict__ x,
                                                         bf16* __restrict__ ft) {
    __shared__ float tile[32][33];
    const int n0 = blockIdx.x * 32;
    const int c0 = blockIdx.y * 32;
    const int b  = blockIdx.z;
    const int tx = threadIdx.x & 7;    // quad index
    const int ty = threadIdx.x >> 3;   // row 0..31

    f32x4 v = *reinterpret_cast<const f32x4*>(
        x + ((size_t)b * CD + c0 + ty) * NN + n0 + tx * 4);
#pragma unroll
    for (int e = 0; e < 4; e++) tile[ty][tx * 4 + e] = v[e];
    __syncthreads();

    bf16x4 o;
#pragma unroll
    for (int e = 0; e < 4; e++) o[e] = (bf16)tile[tx * 4 + e][ty];
    *reinterpret_cast<bf16x4*>(
        ft + ((size_t)b * NN + n0 + ty) * CD + c0 + tx * 4) = o;
}

// ---------------- kernel 2: flash attention + fused residual ----------------
// 512 blocks (8 batch x 64 q-tiles), 256 threads (4 waves, 16 q-rows each).
// KV loop: 64 keys/iter, double-buffered swizzled LDS, 1 barrier/iter.
__global__ __launch_bounds__(256, 2) void attn_kernel(const float* __restrict__ x,
                                                      const bf16* __restrict__ ft,
                                                      float* __restrict__ out) {
    const int tid = threadIdx.x;
    const int w   = tid >> 6;
    const int l   = tid & 63;
    const int l15 = l & 15;
    const int l4  = l >> 4;
    const int l15b4 = (l15 & 7) << 4;   // this lane's row-swizzle key (rows == l15)

    const int batch = blockIdx.x >> 6;
    const int q0    = (blockIdx.x & 63) * QBLK;

    const bf16*  ftb = ft + (size_t)batch * NN * CD;
    const float* xb  = x  + (size_t)batch * CD * NN;

    __shared__ union {
        struct {
            bf16 kt[2][KVB][128];   // [key][c], swizzled      32768 B
            bf16 vt[2][CD][64];     // [c][key], swizzled      32768 B
            bf16 p[4][16][64];      // per-wave [q][key], swz   8192 B
        } s;
        float o[QBLK][CD + 5];      // epilogue (stride 133 dwords -> 2-way max)
    } sm;

    // Q fragments (B of swapped QK^T, A of PV): Q[q=q0+w*16+l15][c=ct*32+l4*8+e]
    bf16x8 qf[4];
    {
        const bf16* qrow = ftb + (size_t)(q0 + w * 16 + l15) * CD + l4 * 8;
#pragma unroll
        for (int ct = 0; ct < 4; ct++)
            qf[ct] = *reinterpret_cast<const bf16x8*>(qrow + ct * 32);
    }

    // staging geometry: 16 lanes per row-chunk
    const int srow = tid >> 4;   // 0..15
    const int sch  = tid & 15;   // 0..15

    bf16x8 kreg[4];
    f32x4  vreg[8];

    auto stage_load = [&](int i0) {
#pragma unroll
        for (int j = 0; j < 4; j++)   // kt: 64 rows x 256B, bf16x8/lane
            kreg[j] = *reinterpret_cast<const bf16x8*>(
                ftb + (size_t)(i0 + j * 16 + srow) * CD + sch * 8);
#pragma unroll
        for (int j = 0; j < 8; j++)   // vt: 128 rows x 256B of x, f32x4/lane
            vreg[j] = *reinterpret_cast<const f32x4*>(
                xb + (size_t)(j * 16 + srow) * NN + i0 + sch * 4);
    };
    auto stage_write = [&](int buf) {
        char* ktb = (char*)sm.s.kt[buf];
        char* vtb = (char*)sm.s.vt[buf];
#pragma unroll
        for (int j = 0; j < 4; j++)
            *reinterpret_cast<bf16x8*>(ktb + KT_BY(j * 16 + srow, sch * 16)) = kreg[j];
#pragma unroll
        for (int j = 0; j < 8; j++) {
            bf16x4 t;
#pragma unroll
            for (int e = 0; e < 4; e++) t[e] = (bf16)vreg[j][e];
            *reinterpret_cast<bf16x4*>(vtb + VT_BY(j * 16 + srow, sch * 8)) = t;
        }
    };

    const f32x4 zero = {0.0f, 0.0f, 0.0f, 0.0f};
    f32x4 oacc[8];
#pragma unroll
    for (int i = 0; i < 8; i++) oacc[i] = zero;
    float m_run = -1e30f;   // running max for q = l15
    float l_par = 0.0f;     // partial denominator over this lane's key share

    stage_load(0);
    stage_write(0);
    __syncthreads();

    for (int it = 0; it < NT; ++it) {
        const int cur = it & 1;
        if (it + 1 < NT) stage_load((it + 1) * KVB);   // in flight during compute

        const char* ktb = (const char*)sm.s.kt[cur];
        const char* vtb = (const char*)sm.s.vt[cur];
        char*       pb  = (char*)sm.s.p[w];

        // ---- swapped QK^T: s[g][r] = S[key=g*16+l4*4+r][q=l15], 16 MFMA ----
        f32x4 s[4];
        __builtin_amdgcn_s_setprio(1);
#pragma unroll
        for (int g = 0; g < 4; g++) {
            s[g] = zero;
#pragma unroll
            for (int ct = 0; ct < 4; ct++) {
                bf16x8 kf = *reinterpret_cast<const bf16x8*>(
                    ktb + KT_BY(g * 16 + l15, ct * 64 + l4 * 16));
                s[g] = __builtin_amdgcn_mfma_f32_16x16x32_bf16(kf, qf[ct], s[g], 0, 0, 0);
            }
        }
        __builtin_amdgcn_s_setprio(0);

        // ---- softmax over keys, in-register ----
        float mp;
        {
            float m0 = fmaxf(fmaxf(s[0][0], s[0][1]), fmaxf(s[0][2], s[0][3]));
            float m1 = fmaxf(fmaxf(s[1][0], s[1][1]), fmaxf(s[1][2], s[1][3]));
            float m2 = fmaxf(fmaxf(s[2][0], s[2][1]), fmaxf(s[2][2], s[2][3]));
            float m3 = fmaxf(fmaxf(s[3][0], s[3][1]), fmaxf(s[3][2], s[3][3]));
            mp = fmaxf(fmaxf(m0, m1), fmaxf(m2, m3));
        }
        mp = fmaxf(mp, __shfl_xor(mp, 16));
        mp = fmaxf(mp, __shfl_xor(mp, 32));

        if (__any(mp > m_run + 8.0f)) {   // defer-max rescale (rare)
            const float mn    = fmaxf(m_run, mp);
            const float alpha = __expf(m_run - mn);
            m_run = mn;
            l_par *= alpha;
            float a[4];
#pragma unroll
            for (int r = 0; r < 4; r++) a[r] = __shfl(alpha, l4 * 4 + r);
#pragma unroll
            for (int ct = 0; ct < 8; ct++)
#pragma unroll
                for (int r = 0; r < 4; r++) oacc[ct][r] *= a[r];
        }

        float pe[4][4];
        float ps = 0.0f;
#pragma unroll
        for (int g = 0; g < 4; g++)
#pragma unroll
            for (int r = 0; r < 4; r++) {
                pe[g][r] = __expf(s[g][r] - m_run);
                ps += pe[g][r];
            }
        l_par += ps;

        // ---- P -> swizzled LDS (b64 writes), read back as A-frags ----
#pragma unroll
        for (int g = 0; g < 4; g++) {
            bf16x4 t;
#pragma unroll
            for (int r = 0; r < 4; r++) t[r] = (bf16)pe[g][r];
            *reinterpret_cast<bf16x4*>(pb + (((int)l15 << 7) +
                ((g * 32 + l4 * 8) ^ l15b4))) = t;
        }
        bf16x8 pf0 = *reinterpret_cast<const bf16x8*>(
            pb + (((int)l15 << 7) + ((l4 * 16) ^ l15b4)));
        bf16x8 pf1 = *reinterpret_cast<const bf16x8*>(
            pb + (((int)l15 << 7) + ((64 + l4 * 16) ^ l15b4)));

        // ---- PV: O[q][c], 16 MFMA ----
        __builtin_amdgcn_s_setprio(1);
#pragma unroll
        for (int ct = 0; ct < 8; ct++) {
            bf16x8 vf0 = *reinterpret_cast<const bf16x8*>(
                vtb + VT_BY(ct * 16 + l15, l4 * 16));
            bf16x8 vf1 = *reinterpret_cast<const bf16x8*>(
                vtb + VT_BY(ct * 16 + l15, 64 + l4 * 16));
            oacc[ct] = __builtin_amdgcn_mfma_f32_16x16x32_bf16(pf0, vf0, oacc[ct], 0, 0, 0);
            oacc[ct] = __builtin_amdgcn_mfma_f32_16x16x32_bf16(pf1, vf1, oacc[ct], 0, 0, 0);
        }
        __builtin_amdgcn_s_setprio(0);

        if (it + 1 < NT) stage_write(cur ^ 1);   // vmcnt wait lands here
        __syncthreads();
    }

    // ---- epilogue: finish deferred sum, normalize, fused residual ----
    float L = l_par;
    L += __shfl_xor(L, 16);
    L += __shfl_xor(L, 32);          // full denominator for q = l15
    float rl[4];
#pragma unroll
    for (int r = 0; r < 4; r++) rl[r] = 1.0f / __shfl(L, l4 * 4 + r);

#pragma unroll
    for (int r = 0; r < 4; r++)
#pragma unroll
        for (int ct = 0; ct < 8; ct++)
            sm.o[w * 16 + l4 * 4 + r][ct * 16 + l15] = oacc[ct][r] * rl[r];
    __syncthreads();

    const size_t xbase = (size_t)batch * CD * NN;
    for (int idx = tid; idx < QBLK * CD; idx += 256) {
        const int c = idx >> 6;
        const int q = idx & 63;
        const size_t g = xbase + (size_t)c * NN + q0 + q;
        out[g] = x[g] + 0.002f * sm.o[q][c];
    }
}

extern "C" void kernel_launch(void* const* d_in, const int* in_sizes, int n_in,
                              void* d_out, int out_size, void* d_ws, size_t ws_size,
                              hipStream_t stream) {
    const float* x = (const float*)d_in[0];
    float* out = (float*)d_out;
    bf16* ft = (bf16*)d_ws;   // 8 MB

    dim3 tb1(256);
    dim3 tg1(NN / 32, CD / 32, BATCH);
    transpose_to_bf16<<<tg1, tb1, 0, stream>>>(x, ft);

    attn_kernel<<<512, 256, 0, stream>>>(x, ft, out);
}